// Round 6
// baseline (215.686 us; speedup 1.0000x reference)
//
#include <hip/hip_runtime.h>
#include <math.h>

#define N_NODES 50000
#define N_EDGES 1600000
#define NFEAT 256
#define NHID 64
#define NCLASS 16

#define PBITS 6
#define PNODES 64                        // nodes per bin
#define NBINS ((N_NODES + PNODES - 1) / PNODES)   // 782
#define BIN_CAP 2560                     // mean 2048, sigma ~45 -> +11 sigma
#define K3_CHUNK 4096
#define K3_THREADS 512
#define K3_PER_T 8                       // 4096 / 512
#define K3_BLOCKS ((N_EDGES + K3_CHUNK - 1) / K3_CHUNK)  // 391

__device__ inline unsigned short f2bf(float f) {     // RNE f32 -> bf16
    unsigned u = __float_as_uint(f);
    return (unsigned short)((u + 0x7FFFu + ((u >> 16) & 1u)) >> 16);
}

// ======================= bin scatter (counting sort, pass 1) ===============
// bin_cursor is COUNT-ONLY (memset 0 by host); slot base is b*BIN_CAP.
// R6: 512 threads (8 waves -> 3 waves/SIMD vs 1.5), 782 bins, 1024-slot scan.
__global__ __launch_bounds__(512) void bin_scatter_kernel(
        const int* __restrict__ src, const int* __restrict__ dst,
        const float* __restrict__ w, int* __restrict__ bin_cursor,
        int2* __restrict__ csr_bin) {
    __shared__ int2 sdata[K3_CHUNK];                 // 32 KB
    __shared__ unsigned short sbinid[K3_CHUNK];      // 8 KB
    __shared__ int swhist[4][NBINS];                 // 12.5 KB (wave-pair priv)
    __shared__ int swcur[4][NBINS];                  // 12.5 KB
    __shared__ int stot[NBINS];
    __shared__ int lscan[NBINS];
    __shared__ int sbase[NBINS];
    __shared__ int stmp[1024];
    int t = threadIdx.x;
    int wv = t >> 7;                                 // 4 copies, 2 waves each
    int base_e = blockIdx.x * K3_CHUNK;

    for (int b = t; b < NBINS; b += K3_THREADS) {
        swhist[0][b] = 0; swhist[1][b] = 0; swhist[2][b] = 0; swhist[3][b] = 0;
    }
    __syncthreads();

    int2 myedge[K3_PER_T];
    short mybin[K3_PER_T];
#pragma unroll
    for (int k = 0; k < K3_PER_T; ++k) {
        int e = base_e + t + k * K3_THREADS;
        if (e < N_EDGES) {
            int d = min(max(dst[e], 0), N_NODES - 1);
            int s = min(max(src[e], 0), N_NODES - 1);
            int b = d >> PBITS;
            mybin[k] = (short)b;
            myedge[k] = make_int2((s << PBITS) | (d & (PNODES - 1)),
                                  __float_as_int(w[e]));
            atomicAdd(&swhist[wv][b], 1);
        } else mybin[k] = -1;
    }
    __syncthreads();
    for (int i = t; i < 1024; i += K3_THREADS) {
        int v = 0;
        if (i < NBINS)
            v = swhist[0][i] + swhist[1][i] + swhist[2][i] + swhist[3][i];
        if (i < NBINS) stot[i] = v;
        stmp[i] = v;
    }
    __syncthreads();
    for (int off = 1; off < 1024; off <<= 1) {
        int i0 = t, i1 = t + 512;
        int v0 = (i0 >= off) ? stmp[i0 - off] : 0;
        int v1 = (i1 >= off) ? stmp[i1 - off] : 0;
        __syncthreads();
        stmp[i0] += v0; stmp[i1] += v1;
        __syncthreads();
    }
    for (int b = t; b < NBINS; b += K3_THREADS) lscan[b] = stmp[b] - stot[b];
    for (int b = t; b < NBINS; b += K3_THREADS) {
        int c = stot[b];
        // count-only cursor: global slot base is b*BIN_CAP + prior count
        if (c > 0) sbase[b] = b * BIN_CAP + atomicAdd(&bin_cursor[b], c);
        int run = lscan[b];
        swcur[0][b] = run; run += swhist[0][b];
        swcur[1][b] = run; run += swhist[1][b];
        swcur[2][b] = run; run += swhist[2][b];
        swcur[3][b] = run;
    }
    __syncthreads();
#pragma unroll
    for (int k = 0; k < K3_PER_T; ++k) {
        int b = mybin[k];
        if (b >= 0) {
            int p = atomicAdd(&swcur[wv][b], 1);
            sdata[p] = myedge[k];
            sbinid[p] = (unsigned short)b;
        }
    }
    __syncthreads();
    int cnt = min(N_EDGES - base_e, K3_CHUNK);
#pragma unroll
    for (int k = 0; k < K3_PER_T; ++k) {
        int p = t + k * K3_THREADS;
        if (p < cnt) {
            int b = sbinid[p];
            int idx = sbase[b] + (p - lscan[b]);
            idx = min(idx, (b + 1) * BIN_CAP - 1);   // overflow-safe (no fault)
            csr_bin[idx] = sdata[p];
        }
    }
}

// ======================= dense GEMM 1 (R13-proven) =========================

#define BK 16
__global__ __launch_bounds__(256) void gemm1_tiled(const float* __restrict__ x,
                                                   const float* __restrict__ W1,
                                                   unsigned short* __restrict__ s1b) {
    __shared__ float xT[BK][68];
    __shared__ float wt[BK][64];
    int t = threadIdx.x;
    int n_base = blockIdx.x * 64;
    int cq = t & 15;
    int nq = t >> 4;
    int ld_node = t >> 2;
    int ld_k4   = (t & 3) * 4;
    int gnode = min(n_base + ld_node, N_NODES - 1);
    const float* xrow = x + (size_t)gnode * NFEAT;
    int wr = t >> 4;
    int wc = (t & 15) * 4;
    float acc[4][4] = {};
    for (int k0 = 0; k0 < NFEAT; k0 += BK) {
        float4 xv = *(const float4*)(xrow + k0 + ld_k4);
        xT[ld_k4 + 0][ld_node] = xv.x;
        xT[ld_k4 + 1][ld_node] = xv.y;
        xT[ld_k4 + 2][ld_node] = xv.z;
        xT[ld_k4 + 3][ld_node] = xv.w;
        *(float4*)&wt[wr][wc] = *(const float4*)(W1 + (size_t)(k0 + wr) * NHID + wc);
        __syncthreads();
#pragma unroll
        for (int k = 0; k < BK; ++k) {
            float4 a = *(const float4*)&xT[k][4 * nq];
            float4 bb = *(const float4*)&wt[k][4 * cq];
            acc[0][0] = fmaf(a.x, bb.x, acc[0][0]);
            acc[0][1] = fmaf(a.x, bb.y, acc[0][1]);
            acc[0][2] = fmaf(a.x, bb.z, acc[0][2]);
            acc[0][3] = fmaf(a.x, bb.w, acc[0][3]);
            acc[1][0] = fmaf(a.y, bb.x, acc[1][0]);
            acc[1][1] = fmaf(a.y, bb.y, acc[1][1]);
            acc[1][2] = fmaf(a.y, bb.z, acc[1][2]);
            acc[1][3] = fmaf(a.y, bb.w, acc[1][3]);
            acc[2][0] = fmaf(a.z, bb.x, acc[2][0]);
            acc[2][1] = fmaf(a.z, bb.y, acc[2][1]);
            acc[2][2] = fmaf(a.z, bb.z, acc[2][2]);
            acc[2][3] = fmaf(a.z, bb.w, acc[2][3]);
            acc[3][0] = fmaf(a.w, bb.x, acc[3][0]);
            acc[3][1] = fmaf(a.w, bb.y, acc[3][1]);
            acc[3][2] = fmaf(a.w, bb.z, acc[3][2]);
            acc[3][3] = fmaf(a.w, bb.w, acc[3][3]);
        }
        __syncthreads();
    }
#pragma unroll
    for (int i = 0; i < 4; ++i) {
        int n = n_base + 4 * nq + i;
        if (n < N_NODES) {
            ushort4 o;
            o.x = f2bf(acc[i][0]); o.y = f2bf(acc[i][1]);
            o.z = f2bf(acc[i][2]); o.w = f2bf(acc[i][3]);
            *(ushort4*)&s1b[(size_t)n * NHID + 4 * cq] = o;
        }
    }
}

// ============ fused per-bin sort + SpMM1 + bias/ReLU + GEMM2 ===============
// R6: 64-node bins -> 782 blocks (3.05/CU vs 1.53), LDS ~41 KB -> 2 blocks/CU
// resident (wave-capped). Structure identical to R5's proven kernel; spmm1
// phase is exactly one round (64 groups x 64 nodes).
__global__ __launch_bounds__(1024, 2) void sort_spmm1_fused(
        const int* __restrict__ bin_cursor, const int2* __restrict__ csr_bin,
        int2* __restrict__ csr_edge, int2* __restrict__ row_range,
        const uint2* __restrict__ s1p2, const float* __restrict__ b1,
        const float* __restrict__ W2, float* __restrict__ s2) {
    __shared__ int2 sdata[BIN_CAP];                  // 20 KB sorted edges
    __shared__ union {
        struct { int whist[16][PNODES]; int wcur[16][PNODES]; } c;  // 8 KB
        float hsh[64][64];                                          // 16 KB
    } u;
    __shared__ int ltot[PNODES];
    __shared__ int ltmp[PNODES];
    __shared__ float W2s[NHID * NCLASS];             // 4 KB
    __shared__ float b1s[NHID];
    int t = threadIdx.x;
    int wv = t >> 6;                                 // 16 waves
    int b = blockIdx.x;
    int base = b * BIN_CAP;
    int cnt = min(bin_cursor[b], BIN_CAP);

    for (int i = t; i < 16 * PNODES; i += 1024) ((int*)u.c.whist)[i] = 0;
    if (t < NHID * NCLASS) W2s[t] = W2[t];
    if (t < NHID) b1s[t] = b1[t];
    __syncthreads();

    // --- hist pass ---
    {
        int j = t;
        for (; j + 1024 < cnt; j += 2048) {
            int2 e0 = csr_bin[base + j];
            int2 e1 = csr_bin[base + j + 1024];
            atomicAdd(&u.c.whist[wv][e0.x & (PNODES - 1)], 1);
            atomicAdd(&u.c.whist[wv][e1.x & (PNODES - 1)], 1);
        }
        if (j < cnt)
            atomicAdd(&u.c.whist[wv][csr_bin[base + j].x & (PNODES - 1)], 1);
    }
    __syncthreads();
    if (t < PNODES) {
        int v = 0;
#pragma unroll
        for (int k = 0; k < 16; ++k) v += u.c.whist[k][t];
        ltot[t] = v; ltmp[t] = v;
    }
    __syncthreads();
    for (int off = 1; off < PNODES; off <<= 1) {
        int a = 0;
        if (t < PNODES && t >= off) a = ltmp[t - off];
        __syncthreads();
        if (t < PNODES) ltmp[t] += a;
        __syncthreads();
    }
    if (t < PNODES) {
        int begl = ltmp[t] - ltot[t];                // local (0-based in bin)
        int node = b * PNODES + t;
        if (node < N_NODES)
            row_range[node] = make_int2(base + begl, base + ltmp[t]);
        int run = begl;
#pragma unroll
        for (int k = 0; k < 16; ++k) { u.c.wcur[k][t] = run; run += u.c.whist[k][t]; }
    }
    __syncthreads();
    // --- scatter pass: sorted (src, w) into LDS ---
    {
        int j = t;
        for (; j + 1024 < cnt; j += 2048) {
            int2 e0 = csr_bin[base + j];
            int2 e1 = csr_bin[base + j + 1024];
            int p0 = atomicAdd(&u.c.wcur[wv][e0.x & (PNODES - 1)], 1);
            int p1 = atomicAdd(&u.c.wcur[wv][e1.x & (PNODES - 1)], 1);
            sdata[p0] = make_int2(e0.x >> PBITS, e0.y);
            sdata[p1] = make_int2(e1.x >> PBITS, e1.y);
        }
        if (j < cnt) {
            int2 e0 = csr_bin[base + j];
            int p0 = atomicAdd(&u.c.wcur[wv][e0.x & (PNODES - 1)], 1);
            sdata[p0] = make_int2(e0.x >> PBITS, e0.y);
        }
    }
    __syncthreads();
    // --- coalesced writeback for spmm2 ---
    for (int i = t; i < cnt; i += 1024) csr_edge[base + i] = sdata[i];

    // --- spmm1 + bias/ReLU + gemm2: 64 node-groups x 16 lanes, one round ---
    int g = t >> 4, lane = t & 15;
    int node = b * PNODES + g;
    if (node >= N_NODES) return;
    int endl = ltmp[g];
    int j = endl - ltot[g];
    float4 accA = {0.f, 0.f, 0.f, 0.f}, accB = {0.f, 0.f, 0.f, 0.f};
    for (; j + 7 < endl; j += 8) {
        int2 e0 = sdata[j],     e1 = sdata[j + 1];
        int2 e2 = sdata[j + 2], e3 = sdata[j + 3];
        int2 e4 = sdata[j + 4], e5 = sdata[j + 5];
        int2 e6 = sdata[j + 6], e7 = sdata[j + 7];
        uint2 v0 = s1p2[(size_t)e0.x * 16 + lane];
        uint2 v1 = s1p2[(size_t)e1.x * 16 + lane];
        uint2 v2 = s1p2[(size_t)e2.x * 16 + lane];
        uint2 v3 = s1p2[(size_t)e3.x * 16 + lane];
        uint2 v4 = s1p2[(size_t)e4.x * 16 + lane];
        uint2 v5 = s1p2[(size_t)e5.x * 16 + lane];
        uint2 v6 = s1p2[(size_t)e6.x * 16 + lane];
        uint2 v7 = s1p2[(size_t)e7.x * 16 + lane];
        float w0 = __int_as_float(e0.y), w1 = __int_as_float(e1.y);
        float w2 = __int_as_float(e2.y), w3 = __int_as_float(e3.y);
        float w4 = __int_as_float(e4.y), w5 = __int_as_float(e5.y);
        float w6 = __int_as_float(e6.y), w7 = __int_as_float(e7.y);
        accA.x = fmaf(w0, __uint_as_float(v0.x << 16), accA.x);
        accA.y = fmaf(w0, __uint_as_float(v0.x & 0xFFFF0000u), accA.y);
        accA.z = fmaf(w0, __uint_as_float(v0.y << 16), accA.z);
        accA.w = fmaf(w0, __uint_as_float(v0.y & 0xFFFF0000u), accA.w);
        accB.x = fmaf(w1, __uint_as_float(v1.x << 16), accB.x);
        accB.y = fmaf(w1, __uint_as_float(v1.x & 0xFFFF0000u), accB.y);
        accB.z = fmaf(w1, __uint_as_float(v1.y << 16), accB.z);
        accB.w = fmaf(w1, __uint_as_float(v1.y & 0xFFFF0000u), accB.w);
        accA.x = fmaf(w2, __uint_as_float(v2.x << 16), accA.x);
        accA.y = fmaf(w2, __uint_as_float(v2.x & 0xFFFF0000u), accA.y);
        accA.z = fmaf(w2, __uint_as_float(v2.y << 16), accA.z);
        accA.w = fmaf(w2, __uint_as_float(v2.y & 0xFFFF0000u), accA.w);
        accB.x = fmaf(w3, __uint_as_float(v3.x << 16), accB.x);
        accB.y = fmaf(w3, __uint_as_float(v3.x & 0xFFFF0000u), accB.y);
        accB.z = fmaf(w3, __uint_as_float(v3.y << 16), accB.z);
        accB.w = fmaf(w3, __uint_as_float(v3.y & 0xFFFF0000u), accB.w);
        accA.x = fmaf(w4, __uint_as_float(v4.x << 16), accA.x);
        accA.y = fmaf(w4, __uint_as_float(v4.x & 0xFFFF0000u), accA.y);
        accA.z = fmaf(w4, __uint_as_float(v4.y << 16), accA.z);
        accA.w = fmaf(w4, __uint_as_float(v4.y & 0xFFFF0000u), accA.w);
        accB.x = fmaf(w5, __uint_as_float(v5.x << 16), accB.x);
        accB.y = fmaf(w5, __uint_as_float(v5.x & 0xFFFF0000u), accB.y);
        accB.z = fmaf(w5, __uint_as_float(v5.y << 16), accB.z);
        accB.w = fmaf(w5, __uint_as_float(v5.y & 0xFFFF0000u), accB.w);
        accA.x = fmaf(w6, __uint_as_float(v6.x << 16), accA.x);
        accA.y = fmaf(w6, __uint_as_float(v6.x & 0xFFFF0000u), accA.y);
        accA.z = fmaf(w6, __uint_as_float(v6.y << 16), accA.z);
        accA.w = fmaf(w6, __uint_as_float(v6.y & 0xFFFF0000u), accA.w);
        accB.x = fmaf(w7, __uint_as_float(v7.x << 16), accB.x);
        accB.y = fmaf(w7, __uint_as_float(v7.x & 0xFFFF0000u), accB.y);
        accB.z = fmaf(w7, __uint_as_float(v7.y << 16), accB.z);
        accB.w = fmaf(w7, __uint_as_float(v7.y & 0xFFFF0000u), accB.w);
    }
    for (; j < endl; ++j) {
        int2 e0 = sdata[j];
        uint2 v0 = s1p2[(size_t)e0.x * 16 + lane];
        float w0 = __int_as_float(e0.y);
        accA.x = fmaf(w0, __uint_as_float(v0.x << 16), accA.x);
        accA.y = fmaf(w0, __uint_as_float(v0.x & 0xFFFF0000u), accA.y);
        accA.z = fmaf(w0, __uint_as_float(v0.y << 16), accA.z);
        accA.w = fmaf(w0, __uint_as_float(v0.y & 0xFFFF0000u), accA.w);
    }
    float4 bb = *(const float4*)&b1s[4 * lane];
    float4 hv;
    hv.x = accA.x + accB.x + bb.x;
    hv.y = accA.y + accB.y + bb.y;
    hv.z = accA.z + accB.z + bb.z;
    hv.w = accA.w + accB.w + bb.w;
    hv.x = hv.x > 0.f ? hv.x : 0.f;
    hv.y = hv.y > 0.f ? hv.y : 0.f;
    hv.z = hv.z > 0.f ? hv.z : 0.f;
    hv.w = hv.w > 0.f ? hv.w : 0.f;
    // same-wave LDS park (lockstep within wave, no barrier needed)
    *(float4*)&u.hsh[g][4 * lane] = hv;
    float acc = 0.f;
#pragma unroll 16
    for (int k = 0; k < NHID; ++k)
        acc = fmaf(u.hsh[g][k], W2s[k * NCLASS + lane], acc);
    s2[(size_t)node * NCLASS + lane] = acc;
}

// ======================= SpMM2 + bias + log_softmax ========================
// R13-exact: fp32 s2, 16 lanes/node, 8-edge unrolled.
__global__ void spmm2_csr_kernel(const int2* __restrict__ row_range,
                                 const int2* __restrict__ csr_edge,
                                 const float* __restrict__ s2,
                                 const float* __restrict__ b2,
                                 float* __restrict__ out) {
    int node = blockIdx.x * 16 + (threadIdx.x >> 4);
    if (node >= N_NODES) return;
    int c = threadIdx.x & 15;
    int2 rr = row_range[node];
    int beg = rr.x, end = rr.y;
    float acc0 = 0.f, acc1 = 0.f, acc2 = 0.f, acc3 = 0.f;
    int j = beg;
    for (; j + 7 < end; j += 8) {
        int2 e0 = csr_edge[j],     e1 = csr_edge[j + 1];
        int2 e2 = csr_edge[j + 2], e3 = csr_edge[j + 3];
        int2 e4 = csr_edge[j + 4], e5 = csr_edge[j + 5];
        int2 e6 = csr_edge[j + 6], e7 = csr_edge[j + 7];
        float g0 = s2[(size_t)e0.x * NCLASS + c];
        float g1 = s2[(size_t)e1.x * NCLASS + c];
        float g2 = s2[(size_t)e2.x * NCLASS + c];
        float g3 = s2[(size_t)e3.x * NCLASS + c];
        float g4 = s2[(size_t)e4.x * NCLASS + c];
        float g5 = s2[(size_t)e5.x * NCLASS + c];
        float g6 = s2[(size_t)e6.x * NCLASS + c];
        float g7 = s2[(size_t)e7.x * NCLASS + c];
        acc0 = fmaf(__int_as_float(e0.y), g0, acc0);
        acc1 = fmaf(__int_as_float(e1.y), g1, acc1);
        acc2 = fmaf(__int_as_float(e2.y), g2, acc2);
        acc3 = fmaf(__int_as_float(e3.y), g3, acc3);
        acc0 = fmaf(__int_as_float(e4.y), g4, acc0);
        acc1 = fmaf(__int_as_float(e5.y), g5, acc1);
        acc2 = fmaf(__int_as_float(e6.y), g6, acc2);
        acc3 = fmaf(__int_as_float(e7.y), g7, acc3);
    }
    for (; j + 3 < end; j += 4) {
        int2 e0 = csr_edge[j],     e1 = csr_edge[j + 1];
        int2 e2 = csr_edge[j + 2], e3 = csr_edge[j + 3];
        acc0 = fmaf(__int_as_float(e0.y), s2[(size_t)e0.x * NCLASS + c], acc0);
        acc1 = fmaf(__int_as_float(e1.y), s2[(size_t)e1.x * NCLASS + c], acc1);
        acc2 = fmaf(__int_as_float(e2.y), s2[(size_t)e2.x * NCLASS + c], acc2);
        acc3 = fmaf(__int_as_float(e3.y), s2[(size_t)e3.x * NCLASS + c], acc3);
    }
    for (; j < end; ++j) {
        int2 e0 = csr_edge[j];
        acc0 = fmaf(__int_as_float(e0.y), s2[(size_t)e0.x * NCLASS + c], acc0);
    }
    float v = (acc0 + acc1) + (acc2 + acc3) + b2[c];
    float mx = v;
    for (int off = 8; off; off >>= 1) mx = fmaxf(mx, __shfl_xor(mx, off, 16));
    float ss = expf(v - mx);
    for (int off = 8; off; off >>= 1) ss += __shfl_xor(ss, off, 16);
    out[(size_t)node * NCLASS + c] = v - mx - logf(ss);
}

// ======================= fallback path (R3 atomic version) =================

__global__ void zero_kernel(float* __restrict__ h, float* __restrict__ out) {
    int i = blockIdx.x * 256 + threadIdx.x;
    if (i < N_NODES * NHID) h[i] = 0.f;
    if (i < N_NODES * NCLASS) out[i] = 0.f;
}

__global__ void gemm1_kernel(const float* __restrict__ x,
                             const float* __restrict__ W1,
                             float* __restrict__ s1) {
    int node = blockIdx.x * 4 + (threadIdx.x >> 6);
    int col  = threadIdx.x & 63;
    if (node >= N_NODES) return;
    const float* xr = x + (size_t)node * NFEAT;
    float sum = 0.f;
#pragma unroll 8
    for (int k = 0; k < NFEAT; ++k)
        sum = fmaf(xr[k], W1[k * NHID + col], sum);
    s1[(size_t)node * NHID + col] = sum;
}

__global__ void spmm1_kernel(const int* __restrict__ src, const int* __restrict__ dst,
                             const float* __restrict__ w, const float* __restrict__ s1,
                             float* __restrict__ h) {
    int e = blockIdx.x * 4 + (threadIdx.x >> 6);
    if (e >= N_EDGES) return;
    int lane = threadIdx.x & 63;
    int s = min(max(src[e], 0), N_NODES - 1);
    int d = min(max(dst[e], 0), N_NODES - 1);
    float v = w[e] * s1[(size_t)s * NHID + lane];
    atomicAdd(&h[(size_t)d * NHID + lane], v);
}

__global__ void bias_relu_kernel(float* __restrict__ h, const float* __restrict__ b1) {
    int i = blockIdx.x * 256 + threadIdx.x;
    if (i >= N_NODES * NHID) return;
    float v = h[i] + b1[i & (NHID - 1)];
    h[i] = v > 0.f ? v : 0.f;
}

__global__ void gemm2_kernel(const float* __restrict__ h,
                             const float* __restrict__ W2,
                             float* __restrict__ s2) {
    int node = blockIdx.x * 16 + (threadIdx.x >> 4);
    int col  = threadIdx.x & 15;
    if (node >= N_NODES) return;
    const float* hr = h + (size_t)node * NHID;
    float sum = 0.f;
#pragma unroll 8
    for (int k = 0; k < NHID; ++k)
        sum = fmaf(hr[k], W2[k * NCLASS + col], sum);
    s2[(size_t)node * NCLASS + col] = sum;
}

__global__ void spmm2_kernel(const int* __restrict__ src, const int* __restrict__ dst,
                             const float* __restrict__ w, const float* __restrict__ s2,
                             float* __restrict__ out) {
    int e = blockIdx.x * 16 + (threadIdx.x >> 4);
    if (e >= N_EDGES) return;
    int lane = threadIdx.x & 15;
    int s = min(max(src[e], 0), N_NODES - 1);
    int d = min(max(dst[e], 0), N_NODES - 1);
    float v = w[e] * s2[(size_t)s * NCLASS + lane];
    atomicAdd(&out[(size_t)d * NCLASS + lane], v);
}

__global__ void logsoftmax_kernel(float* __restrict__ out, const float* __restrict__ b2) {
    int n = blockIdx.x * 256 + threadIdx.x;
    if (n >= N_NODES) return;
    float v[NCLASS];
    float mx = -INFINITY;
#pragma unroll
    for (int c = 0; c < NCLASS; ++c) {
        v[c] = out[(size_t)n * NCLASS + c] + b2[c];
        mx = fmaxf(mx, v[c]);
    }
    float ssum = 0.f;
#pragma unroll
    for (int c = 0; c < NCLASS; ++c) ssum += expf(v[c] - mx);
    float ls = mx + logf(ssum);
#pragma unroll
    for (int c = 0; c < NCLASS; ++c) out[(size_t)n * NCLASS + c] = v[c] - ls;
}

// ======================= launch ============================================

extern "C" void kernel_launch(void* const* d_in, const int* in_sizes, int n_in,
                              void* d_out, int out_size, void* d_ws, size_t ws_size,
                              hipStream_t stream) {
    if (n_in != 8) return;
    const int expected[8] = { N_NODES * NFEAT, NFEAT * NHID, NHID,
                              NHID * NCLASS, NCLASS, N_EDGES, N_EDGES, N_EDGES };
    for (int i = 0; i < 8; ++i)
        if (in_sizes[i] != expected[i]) return;
    if (out_size != N_NODES * NCLASS) return;

    const float* x  = (const float*)d_in[0];
    const float* W1 = (const float*)d_in[1];
    const float* b1 = (const float*)d_in[2];
    const float* W2 = (const float*)d_in[3];
    const float* b2 = (const float*)d_in[4];
    const int* edge_src = (const int*)d_in[5];
    const int* edge_dst = (const int*)d_in[6];
    const float* edge_w = (const float*)d_in[7];
    float* out = (float*)d_out;

    const size_t S1_ELTS = (size_t)N_NODES * NHID;          // 3.2M (ushorts)
    const size_t CAP_WORDS = (size_t)NBINS * BIN_CAP * 2;   // int2 region, words
    // layout (32-bit words) — fully DISJOINT (s1b live alongside csr_bin
    // inside sort_spmm1_fused):
    //   [0, CAP)          csr_bin    (16 MB)
    //   [CAP, 2CAP)       csr_edge   (16 MB)
    //   [2CAP, +2N)       row_range  (0.4 MB)
    //   [.., +1024)       bin_cursor (782 ints + pad, keeps s1b 8B-aligned)
    //   [.., +S1/2)       s1b        (6.4 MB bf16)
    //   [.., +N*NCLASS)   s2         (3.2 MB fp32)
    const size_t NEW_WORDS = 2 * CAP_WORDS + 2 * (size_t)N_NODES + 1024
                           + S1_ELTS / 2 + (size_t)N_NODES * NCLASS;
    if (ws_size >= NEW_WORDS * 4) {
        int2*  csr_bin    = (int2*)d_ws;
        int2*  csr_edge   = (int2*)((int*)d_ws + CAP_WORDS);
        int2*  row_range  = (int2*)((int*)d_ws + 2 * CAP_WORDS);
        int*   bin_cursor = (int*)d_ws + 2 * CAP_WORDS + 2 * (size_t)N_NODES;
        unsigned short* s1b =
            (unsigned short*)((int*)d_ws + 2 * CAP_WORDS + 2 * (size_t)N_NODES + 1024);
        float* s2 = (float*)d_ws + 2 * CAP_WORDS + 2 * (size_t)N_NODES + 1024
                  + S1_ELTS / 2;

        hipMemsetAsync(bin_cursor, 0, NBINS * sizeof(int), stream);
        bin_scatter_kernel<<<K3_BLOCKS, K3_THREADS, 0, stream>>>(
            edge_src, edge_dst, edge_w, bin_cursor, csr_bin);
        gemm1_tiled<<<(N_NODES + 63) / 64, 256, 0, stream>>>(x, W1, s1b);
        sort_spmm1_fused<<<NBINS, 1024, 0, stream>>>(
            bin_cursor, csr_bin, csr_edge, row_range,
            (const uint2*)s1b, b1, W2, s2);
        spmm2_csr_kernel<<<(N_NODES + 15) / 16, 256, 0, stream>>>(
            row_range, csr_edge, s2, b2, out);
        return;
    }

    // --- fallback: proven atomic path (25.6 MB ws) ---
    if (ws_size < 2 * S1_ELTS * sizeof(float)) return;
    float* s1 = (float*)d_ws;
    float* h  = s1 + S1_ELTS;
    float* s2 = s1;
    zero_kernel<<<(N_NODES * NHID + 255) / 256, 256, 0, stream>>>(h, out);
    gemm1_kernel<<<(N_NODES + 3) / 4, 256, 0, stream>>>(x, W1, s1);
    spmm1_kernel<<<(N_EDGES + 3) / 4, 256, 0, stream>>>(edge_src, edge_dst, edge_w, s1, h);
    bias_relu_kernel<<<(N_NODES * NHID + 255) / 256, 256, 0, stream>>>(h, b1);
    gemm2_kernel<<<(N_NODES + 15) / 16, 256, 0, stream>>>(h, W2, s2);
    spmm2_kernel<<<(N_EDGES + 15) / 16, 256, 0, stream>>>(edge_src, edge_dst, edge_w, s2, out);
    logsoftmax_kernel<<<(N_NODES + 255) / 256, 256, 0, stream>>>(out, b2);
}